// Round 14
// baseline (244.060 us; speedup 1.0000x reference)
//
#include <hip/hip_runtime.h>
#include <hip/hip_cooperative_groups.h>

namespace cg = cooperative_groups;

#define B_  8
#define N_  8192
#define S_  2048
#define C1_ 128
#define C2_ 256
#define KA_ 384   // C1_+C2_
#define H0_ 256
#define H1_ 128
#define R_  (B_ * N_)   // 65536

typedef __bf16 bf16;
typedef __attribute__((ext_vector_type(2))) __bf16 bf16x2;
typedef __attribute__((ext_vector_type(4))) __bf16 bf16x4;
typedef __attribute__((ext_vector_type(8))) __bf16 bf16x8;
typedef __attribute__((ext_vector_type(4))) float f32x4;

__device__ __forceinline__ void gload_lds16(const void* g, void* l) {
    __builtin_amdgcn_global_load_lds(
        (const __attribute__((address_space(1))) void*)g,
        (__attribute__((address_space(3))) void*)l, 16, 0, 0);
}

// ---- prep: w0 cvt (0..95) | w1 cvt (96..127) | zero stats (128) | pack xyz2 (129..192)
__global__ __launch_bounds__(256) void prep_kernel(const float* __restrict__ w0,
                                                   const float* __restrict__ w1,
                                                   const float* __restrict__ xyz2,
                                                   bf16* __restrict__ Wbf0,
                                                   bf16* __restrict__ Wbf1,
                                                   float* __restrict__ stats,
                                                   float4* __restrict__ c4g)
{
    int blk = blockIdx.x, tid = threadIdx.x;
    if (blk < 96) {
        int i = blk * 256 + tid;
        float4 v = *(const float4*)(w0 + (size_t)i * 4);
        bf16x4 o = { (bf16)v.x, (bf16)v.y, (bf16)v.z, (bf16)v.w };
        *(bf16x4*)(Wbf0 + (size_t)i * 4) = o;
    } else if (blk < 128) {
        int i = (blk - 96) * 256 + tid;
        float4 v = *(const float4*)(w1 + (size_t)i * 4);
        bf16x4 o = { (bf16)v.x, (bf16)v.y, (bf16)v.z, (bf16)v.w };
        *(bf16x4*)(Wbf1 + (size_t)i * 4) = o;
    } else if (blk == 128) {
        #pragma unroll
        for (int k = 0; k < 3; ++k) stats[k * 256 + tid] = 0.f;
    } else {
        int i = (blk - 129) * 256 + tid;
        float x = xyz2[(size_t)i * 3 + 0];
        float y = xyz2[(size_t)i * 3 + 1];
        float z = xyz2[(size_t)i * 3 + 2];
        float4 c; c.x = x; c.y = y; c.z = z; c.w = x * x + y * y + z * z;
        c4g[i] = c;
    }
}

// ---------------- top-3 NN + fused gather/interp + p1 cast ----------------------
// R11-exact. LDS scan (branchy split-4, 1 q/thread) + LDS merge; XCD swizzle
// keeps points2 L2-local. Do NOT restructure the scan/merge: Q-blocking (R4),
// branchless (R6), global/L1 scan (R10), shfl merge (R12) all regressed.
__global__ __launch_bounds__(256) void top3_interp_kernel(
    const float* __restrict__ xyz1, const float4* __restrict__ c4g,
    const float* __restrict__ points1, const float* __restrict__ points2,
    bf16* __restrict__ Abf)
{
    __shared__ float4 sc[S_];          // 32 KB: (x,y,z,|c|^2)
    __shared__ float  md[64][4][3];    // 3 KB
    __shared__ int    mi[64][4][3];    // 3 KB
    __shared__ int    sidx[64][3];     // 768 B
    __shared__ float  sw[64][3];       // 768 B

    // bijective XCD swizzle (1024 = 8*128): XCD (bid&7) owns batch (bid&7)
    int swz = (blockIdx.x & 7) * 128 + (blockIdx.x >> 3);
    int b = swz >> 7;
    int ntile = swz & 127;

    const float4* cand = c4g + (size_t)b * S_;
    for (int i = threadIdx.x; i < S_; i += 256)
        sc[i] = cand[i];
    __syncthreads();

    const int q  = threadIdx.x >> 2;   // [0,64)
    const int sp = threadIdx.x & 3;    // [0,4)
    const size_t row = (size_t)b * N_ + ntile * 64 + q;
    const float ax = -2.f * xyz1[row * 3 + 0];
    const float ay = -2.f * xyz1[row * 3 + 1];
    const float az = -2.f * xyz1[row * 3 + 2];

    float m0 = 1e30f, m1 = 1e30f, m2 = 1e30f;
    int   j0 = 0, j1 = 0, j2 = 0;

    #pragma unroll 4
    for (int i = 0; i < S_ / 4; ++i) {
        int s = i * 4 + sp;
        float4 c = sc[s];
        float m = fmaf(ax, c.x, fmaf(ay, c.y, fmaf(az, c.z, c.w)));
        if (m < m2) {
            if (m < m1) {
                m2 = m1; j2 = j1;
                if (m < m0) { m1 = m0; j1 = j0; m0 = m; j0 = s; }
                else        { m1 = m;  j1 = s; }
            } else { m2 = m; j2 = s; }
        }
    }
    md[q][sp][0] = m0; md[q][sp][1] = m1; md[q][sp][2] = m2;
    mi[q][sp][0] = j0; mi[q][sp][1] = j1; mi[q][sp][2] = j2;
    __syncthreads();

    if (threadIdx.x < 64) {
        int qq = threadIdx.x;
        float d0 = md[qq][0][0], d1 = md[qq][0][1], d2 = md[qq][0][2];
        int   i0 = mi[qq][0][0], i1 = mi[qq][0][1], i2 = mi[qq][0][2];
        #pragma unroll
        for (int p = 1; p < 4; ++p) {
            #pragma unroll
            for (int j = 0; j < 3; ++j) {
                float d = md[qq][p][j]; int s = mi[qq][p][j];
                bool lt2 = (d < d2) || (d == d2 && s < i2);
                if (lt2) {
                    bool lt1 = (d < d1) || (d == d1 && s < i1);
                    if (lt1) {
                        d2 = d1; i2 = i1;
                        bool lt0 = (d < d0) || (d == d0 && s < i0);
                        if (lt0) { d1 = d0; i1 = i0; d0 = d; i0 = s; }
                        else     { d1 = d;  i1 = s; }
                    } else { d2 = d; i2 = s; }
                }
            }
        }
        size_t orow = (size_t)b * N_ + ntile * 64 + qq;
        float px = xyz1[orow * 3 + 0], py = xyz1[orow * 3 + 1], pz = xyz1[orow * 3 + 2];
        float pp = px * px + py * py + pz * pz;
        float r0 = 1.f / (d0 + pp + 1e-8f);
        float r1 = 1.f / (d1 + pp + 1e-8f);
        float r2 = 1.f / (d2 + pp + 1e-8f);
        float inv = 1.f / (r0 + r1 + r2);
        sidx[qq][0] = i0; sidx[qq][1] = i1; sidx[qq][2] = i2;
        sw[qq][0] = r0 * inv; sw[qq][1] = r1 * inv; sw[qq][2] = r2 * inv;
    }
    __syncthreads();

    // gather + interp + p1 cast. Wave wv handles rows wv, wv+4, ...
    const int wv = threadIdx.x >> 6, ln = threadIdx.x & 63;
    const size_t rowbase = (size_t)b * N_ + ntile * 64;
    const float* p2 = points2 + (size_t)b * S_ * C2_;
    for (int r = wv; r < 64; r += 4) {
        size_t orow = rowbase + r;
        int ia = sidx[r][0], ib = sidx[r][1], ic = sidx[r][2];
        float wa = sw[r][0], wb = sw[r][1], wc = sw[r][2];
        float4 va = *(const float4*)(p2 + (size_t)ia * C2_ + ln * 4);
        float4 vb = *(const float4*)(p2 + (size_t)ib * C2_ + ln * 4);
        float4 vc = *(const float4*)(p2 + (size_t)ic * C2_ + ln * 4);
        bf16x4 o = { (bf16)(wa * va.x + wb * vb.x + wc * vc.x),
                     (bf16)(wa * va.y + wb * vb.y + wc * vc.y),
                     (bf16)(wa * va.z + wb * vb.z + wc * vc.z),
                     (bf16)(wa * va.w + wb * vb.w + wc * vc.w) };
        *(bf16x4*)(Abf + orow * KA_ + C1_ + ln * 4) = o;

        float2 p = *(const float2*)(points1 + orow * C1_ + ln * 2);
        bf16x2 po = { (bf16)p.x, (bf16)p.y };
        *(bf16x2*)(Abf + orow * KA_ + ln * 2) = po;
    }
}

// ---------------- MFMA bf16 GEMM1 with fused BN-stats epilogue ------------------
template<int K, int OT, bool OUTBF>
__global__ __launch_bounds__(256) void mfma_gemm_kernel(
    const bf16* __restrict__ A, const bf16* __restrict__ Wt, void* __restrict__ Cout,
    float* __restrict__ sums, float* __restrict__ sumsq)
{
    __shared__ bf16 As[128 * 32];
    __shared__ bf16 Bs[128 * 32];
    __shared__ float csum[128], csumsq[128];
    const int tid = threadIdx.x;
    const int lane = tid & 63, wave = tid >> 6;
    const int wr = wave >> 1, wc = wave & 1;
    const int r0 = blockIdx.x * 128, o0 = blockIdx.y * 128;

    f32x4 acc[4][4] = {};

    const int l15 = lane & 15, g = lane >> 4;
    const int slot = g ^ ((l15 >> 1) & 3);
    int a_off[4], b_off[4];
    #pragma unroll
    for (int m = 0; m < 4; ++m) a_off[m] = (wr * 64 + m * 16 + l15) * 32 + slot * 8;
    #pragma unroll
    for (int n = 0; n < 4; ++n) b_off[n] = (wc * 64 + n * 16 + l15) * 32 + slot * 8;

    const int c0 = tid, c1 = tid + 256;
    const int ar0 = c0 >> 2, ar1 = c1 >> 2;
    const int kb0 = ((c0 & 3) ^ ((ar0 >> 1) & 3)) * 8;
    const int kb1 = ((c1 & 3) ^ ((ar1 >> 1) & 3)) * 8;

    if (tid < 128) { csum[tid] = 0.f; csumsq[tid] = 0.f; }

    for (int k0 = 0; k0 < K; k0 += 32) {
        __syncthreads();
        gload_lds16(A  + (size_t)(r0 + ar0) * K + k0 + kb0, &As[c0 * 8]);
        gload_lds16(A  + (size_t)(r0 + ar1) * K + k0 + kb1, &As[c1 * 8]);
        gload_lds16(Wt + (size_t)(o0 + ar0) * K + k0 + kb0, &Bs[c0 * 8]);
        gload_lds16(Wt + (size_t)(o0 + ar1) * K + k0 + kb1, &Bs[c1 * 8]);
        __syncthreads();
        bf16x8 af[4], bfr[4];
        #pragma unroll
        for (int m = 0; m < 4; ++m) af[m]  = *(const bf16x8*)&As[a_off[m]];
        #pragma unroll
        for (int n = 0; n < 4; ++n) bfr[n] = *(const bf16x8*)&Bs[b_off[n]];
        #pragma unroll
        for (int m = 0; m < 4; ++m)
            #pragma unroll
            for (int n = 0; n < 4; ++n)
                acc[m][n] = __builtin_amdgcn_mfma_f32_16x16x32_bf16(af[m], bfr[n], acc[m][n], 0, 0, 0);
    }

    const int crow = r0 + wr * 64 + g * 4;
    const int ccol = o0 + wc * 64 + l15;
    #pragma unroll
    for (int m = 0; m < 4; ++m)
        #pragma unroll
        for (int n = 0; n < 4; ++n)
            #pragma unroll
            for (int j = 0; j < 4; ++j) {
                size_t off = (size_t)(crow + m * 16 + j) * OT + ccol + n * 16;
                if (OUTBF) ((bf16*)Cout)[off] = (bf16)acc[m][n][j];
                else       ((float*)Cout)[off] = acc[m][n][j];
            }

    #pragma unroll
    for (int n = 0; n < 4; ++n) {
        float s = 0.f, q = 0.f;
        #pragma unroll
        for (int m = 0; m < 4; ++m)
            #pragma unroll
            for (int j = 0; j < 4; ++j) {
                float v = acc[m][n][j];
                s += v; q = fmaf(v, v, q);
            }
        int col = wc * 64 + n * 16 + l15;
        atomicAdd(&csum[col], s);
        atomicAdd(&csumsq[col], q);
    }
    __syncthreads();
    if (tid < 128) {
        atomicAdd(&sums[o0 + tid], csum[tid]);
        atomicAdd(&sumsq[o0 + tid], csumsq[tid]);
    }
}

// ---------------- MFMA GEMM2 (cooperative): finalize0 + BN0+ReLU at A-staging,
// stats1 atomics -> grid.sync -> finalize1 + BN1+ReLU applied to acc -> single write.
__global__ __launch_bounds__(256, 2) void mfma_gemm2_kernel(
    const bf16* __restrict__ Ahp, const bf16* __restrict__ Wt,
    const float* __restrict__ sums0, const float* __restrict__ sumsq0,
    const float* __restrict__ g0, const float* __restrict__ be0,
    const float* __restrict__ g1, const float* __restrict__ be1,
    float* __restrict__ Cout, float* __restrict__ sums, float* __restrict__ sumsq)
{
    constexpr int K = H0_, OT = H1_;
    __shared__ bf16 As[128 * 32];
    __shared__ bf16 Bs[128 * 32];
    __shared__ float csum[128], csumsq[128];
    __shared__ float sscale[256], sshift[256];
    const int tid = threadIdx.x;
    const int lane = tid & 63, wave = tid >> 6;
    const int wr = wave >> 1, wc = wave & 1;
    const int r0 = blockIdx.x * 128, o0 = 0;

    {
        const float invR = 1.f / (float)R_;
        float mean = sums0[tid] * invR;
        float var = sumsq0[tid] * invR - mean * mean;
        float sv = g0[tid] * rsqrtf(var + 1e-5f);
        sscale[tid] = sv;
        sshift[tid] = be0[tid] - mean * sv;
    }
    if (tid < 128) { csum[tid] = 0.f; csumsq[tid] = 0.f; }
    __syncthreads();

    f32x4 acc[4][4] = {};

    const int l15 = lane & 15, g = lane >> 4;
    const int slot = g ^ ((l15 >> 1) & 3);
    int a_off[4], b_off[4];
    #pragma unroll
    for (int m = 0; m < 4; ++m) a_off[m] = (wr * 64 + m * 16 + l15) * 32 + slot * 8;
    #pragma unroll
    for (int n = 0; n < 4; ++n) b_off[n] = (wc * 64 + n * 16 + l15) * 32 + slot * 8;

    const int c0 = tid, c1 = tid + 256;
    const int ar0 = c0 >> 2, ar1 = c1 >> 2;
    const int kb0 = ((c0 & 3) ^ ((ar0 >> 1) & 3)) * 8;
    const int kb1 = ((c1 & 3) ^ ((ar1 >> 1) & 3)) * 8;

    for (int k0 = 0; k0 < K; k0 += 32) {
        bf16x8 va0 = *(const bf16x8*)(Ahp + (size_t)(r0 + ar0) * K + k0 + kb0);
        bf16x8 va1 = *(const bf16x8*)(Ahp + (size_t)(r0 + ar1) * K + k0 + kb1);
        float s0a[8], h0a[8], s1a[8], h1a[8];
        *(float4*)&s0a[0] = *(const float4*)(&sscale[k0 + kb0]);
        *(float4*)&s0a[4] = *(const float4*)(&sscale[k0 + kb0 + 4]);
        *(float4*)&h0a[0] = *(const float4*)(&sshift[k0 + kb0]);
        *(float4*)&h0a[4] = *(const float4*)(&sshift[k0 + kb0 + 4]);
        *(float4*)&s1a[0] = *(const float4*)(&sscale[k0 + kb1]);
        *(float4*)&s1a[4] = *(const float4*)(&sscale[k0 + kb1 + 4]);
        *(float4*)&h1a[0] = *(const float4*)(&sshift[k0 + kb1]);
        *(float4*)&h1a[4] = *(const float4*)(&sshift[k0 + kb1 + 4]);
        bf16x8 ra0, ra1;
        #pragma unroll
        for (int j = 0; j < 8; ++j) {
            float f0 = fmaxf(0.f, fmaf((float)va0[j], s0a[j], h0a[j]));
            float f1 = fmaxf(0.f, fmaf((float)va1[j], s1a[j], h1a[j]));
            ra0[j] = (bf16)f0; ra1[j] = (bf16)f1;
        }
        __syncthreads();
        gload_lds16(Wt + (size_t)(o0 + ar0) * K + k0 + kb0, &Bs[c0 * 8]);
        gload_lds16(Wt + (size_t)(o0 + ar1) * K + k0 + kb1, &Bs[c1 * 8]);
        *(bf16x8*)&As[c0 * 8] = ra0;
        *(bf16x8*)&As[c1 * 8] = ra1;
        __syncthreads();
        bf16x8 af[4], bfr[4];
        #pragma unroll
        for (int m = 0; m < 4; ++m) af[m]  = *(const bf16x8*)&As[a_off[m]];
        #pragma unroll
        for (int n = 0; n < 4; ++n) bfr[n] = *(const bf16x8*)&Bs[b_off[n]];
        #pragma unroll
        for (int m = 0; m < 4; ++m)
            #pragma unroll
            for (int n = 0; n < 4; ++n)
                acc[m][n] = __builtin_amdgcn_mfma_f32_16x16x32_bf16(af[m], bfr[n], acc[m][n], 0, 0, 0);
    }

    // stats1 from registers (no C write yet)
    #pragma unroll
    for (int n = 0; n < 4; ++n) {
        float s = 0.f, q = 0.f;
        #pragma unroll
        for (int m = 0; m < 4; ++m)
            #pragma unroll
            for (int j = 0; j < 4; ++j) {
                float v = acc[m][n][j];
                s += v; q = fmaf(v, v, q);
            }
        int col = wc * 64 + n * 16 + l15;
        atomicAdd(&csum[col], s);
        atomicAdd(&csumsq[col], q);
    }
    __syncthreads();
    if (tid < 128) {
        atomicAdd(&sums[tid], csum[tid]);
        atomicAdd(&sumsq[tid], csumsq[tid]);
    }
    __threadfence();
    cg::this_grid().sync();

    // finalize1 (redundant per block) into reused csum/csumsq
    if (tid < 128) {
        const float invR = 1.f / (float)R_;
        float sv_sum = __hip_atomic_load(&sums[tid], __ATOMIC_RELAXED, __HIP_MEMORY_SCOPE_AGENT);
        float sv_sq  = __hip_atomic_load(&sumsq[tid], __ATOMIC_RELAXED, __HIP_MEMORY_SCOPE_AGENT);
        float mean = sv_sum * invR;
        float var = sv_sq * invR - mean * mean;
        float sv = g1[tid] * rsqrtf(var + 1e-5f);
        csum[tid] = sv;
        csumsq[tid] = be1[tid] - mean * sv;
    }
    __syncthreads();

    // apply BN1+ReLU to acc and write out (single pass)
    const int crow = r0 + wr * 64 + g * 4;
    const int ccol = o0 + wc * 64 + l15;
    #pragma unroll
    for (int n = 0; n < 4; ++n) {
        int col = ccol + n * 16;
        float sv = csum[col], sh = csumsq[col];
        #pragma unroll
        for (int m = 0; m < 4; ++m)
            #pragma unroll
            for (int j = 0; j < 4; ++j) {
                float v = fmaxf(0.f, fmaf(acc[m][n][j], sv, sh));
                Cout[(size_t)(crow + m * 16 + j) * OT + col] = v;
            }
    }
}

extern "C" void kernel_launch(void* const* d_in, const int* in_sizes, int n_in,
                              void* d_out, int out_size, void* d_ws, size_t ws_size,
                              hipStream_t stream)
{
    const float* xyz1    = (const float*)d_in[0];
    const float* xyz2    = (const float*)d_in[1];
    const float* points1 = (const float*)d_in[2];
    const float* points2 = (const float*)d_in[3];
    const float* w0  = (const float*)d_in[4];
    const float* g0  = (const float*)d_in[6];
    const float* be0 = (const float*)d_in[7];
    const float* w1  = (const float*)d_in[8];
    const float* g1  = (const float*)d_in[10];
    const float* be1 = (const float*)d_in[11];
    float* out = (float*)d_out;
    char* ws = (char*)d_ws;

    bf16* Abf     = (bf16*)(ws);                    // 65536*384*2
    bf16* hpre_bf = (bf16*)(ws + 50331648);         // 65536*256*2
    bf16* Wbf0    = (bf16*)(ws + 117440512);        // 256*384*2
    bf16* Wbf1    = (bf16*)(ws + 117637120);        // 128*256*2
    float* stats  = (float*)(ws + 119275520);       // 768*4
    float4* c4g   = (float4*)(ws + 119279616);      // 16384*16
    float* sums0 = stats,        *sumsq0 = stats + 256;
    float* sums1 = stats + 512,  *sumsq1 = stats + 640;

    prep_kernel<<<193, 256, 0, stream>>>(w0, w1, xyz2, Wbf0, Wbf1, stats, c4g);
    top3_interp_kernel<<<B_ * (N_ / 64), 256, 0, stream>>>(xyz1, c4g, points1, points2, Abf);

    mfma_gemm_kernel<KA_, H0_, true><<<dim3(R_ / 128, 2), 256, 0, stream>>>(
        Abf, Wbf0, hpre_bf, sums0, sumsq0);

    void* args[] = { (void*)&hpre_bf, (void*)&Wbf1, (void*)&sums0, (void*)&sumsq0,
                     (void*)&g0, (void*)&be0, (void*)&g1, (void*)&be1,
                     (void*)&out, (void*)&sums1, (void*)&sumsq1 };
    hipLaunchCooperativeKernel((void*)mfma_gemm2_kernel, dim3(R_ / 128), dim3(256),
                               args, 0, stream);
}

// Round 15
// 159.230 us; speedup vs baseline: 1.5328x; 1.5328x over previous
//
#include <hip/hip_runtime.h>

#define B_  8
#define N_  8192
#define S_  2048
#define C1_ 128
#define C2_ 256
#define KA_ 384   // C1_+C2_
#define H0_ 256
#define H1_ 128
#define R_  (B_ * N_)   // 65536

typedef __bf16 bf16;
typedef __attribute__((ext_vector_type(2))) __bf16 bf16x2;
typedef __attribute__((ext_vector_type(4))) __bf16 bf16x4;
typedef __attribute__((ext_vector_type(8))) __bf16 bf16x8;
typedef __attribute__((ext_vector_type(4))) float f32x4;

__device__ __forceinline__ void gload_lds16(const void* g, void* l) {
    __builtin_amdgcn_global_load_lds(
        (const __attribute__((address_space(1))) void*)g,
        (__attribute__((address_space(3))) void*)l, 16, 0, 0);
}

// ---- prep: w0 cvt (0..95) | w1 cvt (96..127) | zero stats (128) | pack xyz2 (129..192)
__global__ __launch_bounds__(256) void prep_kernel(const float* __restrict__ w0,
                                                   const float* __restrict__ w1,
                                                   const float* __restrict__ xyz2,
                                                   bf16* __restrict__ Wbf0,
                                                   bf16* __restrict__ Wbf1,
                                                   float* __restrict__ stats,
                                                   float4* __restrict__ c4g)
{
    int blk = blockIdx.x, tid = threadIdx.x;
    if (blk < 96) {
        int i = blk * 256 + tid;
        float4 v = *(const float4*)(w0 + (size_t)i * 4);
        bf16x4 o = { (bf16)v.x, (bf16)v.y, (bf16)v.z, (bf16)v.w };
        *(bf16x4*)(Wbf0 + (size_t)i * 4) = o;
    } else if (blk < 128) {
        int i = (blk - 96) * 256 + tid;
        float4 v = *(const float4*)(w1 + (size_t)i * 4);
        bf16x4 o = { (bf16)v.x, (bf16)v.y, (bf16)v.z, (bf16)v.w };
        *(bf16x4*)(Wbf1 + (size_t)i * 4) = o;
    } else if (blk == 128) {
        #pragma unroll
        for (int k = 0; k < 3; ++k) stats[k * 256 + tid] = 0.f;
    } else {
        int i = (blk - 129) * 256 + tid;
        float x = xyz2[(size_t)i * 3 + 0];
        float y = xyz2[(size_t)i * 3 + 1];
        float z = xyz2[(size_t)i * 3 + 2];
        float4 c; c.x = x; c.y = y; c.z = z; c.w = x * x + y * y + z * z;
        c4g[i] = c;
    }
}

// ---------------- top-3 NN + fused gather/interp + p1 cast ----------------------
// R11/R13-exact. LDS scan (branchy split-4, 1 q/thread) + LDS merge; XCD swizzle
// keeps points2 L2-local. Do NOT restructure the scan/merge: Q-blocking (R4),
// branchless (R6), global/L1 scan (R10), shfl merge (R12), coop-sync (R14)
// all regressed.
__global__ __launch_bounds__(256) void top3_interp_kernel(
    const float* __restrict__ xyz1, const float4* __restrict__ c4g,
    const float* __restrict__ points1, const float* __restrict__ points2,
    bf16* __restrict__ Abf)
{
    __shared__ float4 sc[S_];          // 32 KB: (x,y,z,|c|^2)
    __shared__ float  md[64][4][3];    // 3 KB
    __shared__ int    mi[64][4][3];    // 3 KB
    __shared__ int    sidx[64][3];     // 768 B
    __shared__ float  sw[64][3];       // 768 B

    // bijective XCD swizzle (1024 = 8*128): XCD (bid&7) owns batch (bid&7)
    int swz = (blockIdx.x & 7) * 128 + (blockIdx.x >> 3);
    int b = swz >> 7;
    int ntile = swz & 127;

    const float4* cand = c4g + (size_t)b * S_;
    for (int i = threadIdx.x; i < S_; i += 256)
        sc[i] = cand[i];
    __syncthreads();

    const int q  = threadIdx.x >> 2;   // [0,64)
    const int sp = threadIdx.x & 3;    // [0,4)
    const size_t row = (size_t)b * N_ + ntile * 64 + q;
    const float ax = -2.f * xyz1[row * 3 + 0];
    const float ay = -2.f * xyz1[row * 3 + 1];
    const float az = -2.f * xyz1[row * 3 + 2];

    float m0 = 1e30f, m1 = 1e30f, m2 = 1e30f;
    int   j0 = 0, j1 = 0, j2 = 0;

    #pragma unroll 4
    for (int i = 0; i < S_ / 4; ++i) {
        int s = i * 4 + sp;
        float4 c = sc[s];
        float m = fmaf(ax, c.x, fmaf(ay, c.y, fmaf(az, c.z, c.w)));
        if (m < m2) {
            if (m < m1) {
                m2 = m1; j2 = j1;
                if (m < m0) { m1 = m0; j1 = j0; m0 = m; j0 = s; }
                else        { m1 = m;  j1 = s; }
            } else { m2 = m; j2 = s; }
        }
    }
    md[q][sp][0] = m0; md[q][sp][1] = m1; md[q][sp][2] = m2;
    mi[q][sp][0] = j0; mi[q][sp][1] = j1; mi[q][sp][2] = j2;
    __syncthreads();

    if (threadIdx.x < 64) {
        int qq = threadIdx.x;
        float d0 = md[qq][0][0], d1 = md[qq][0][1], d2 = md[qq][0][2];
        int   i0 = mi[qq][0][0], i1 = mi[qq][0][1], i2 = mi[qq][0][2];
        #pragma unroll
        for (int p = 1; p < 4; ++p) {
            #pragma unroll
            for (int j = 0; j < 3; ++j) {
                float d = md[qq][p][j]; int s = mi[qq][p][j];
                bool lt2 = (d < d2) || (d == d2 && s < i2);
                if (lt2) {
                    bool lt1 = (d < d1) || (d == d1 && s < i1);
                    if (lt1) {
                        d2 = d1; i2 = i1;
                        bool lt0 = (d < d0) || (d == d0 && s < i0);
                        if (lt0) { d1 = d0; i1 = i0; d0 = d; i0 = s; }
                        else     { d1 = d;  i1 = s; }
                    } else { d2 = d; i2 = s; }
                }
            }
        }
        size_t orow = (size_t)b * N_ + ntile * 64 + qq;
        float px = xyz1[orow * 3 + 0], py = xyz1[orow * 3 + 1], pz = xyz1[orow * 3 + 2];
        float pp = px * px + py * py + pz * pz;
        float r0 = 1.f / (d0 + pp + 1e-8f);
        float r1 = 1.f / (d1 + pp + 1e-8f);
        float r2 = 1.f / (d2 + pp + 1e-8f);
        float inv = 1.f / (r0 + r1 + r2);
        sidx[qq][0] = i0; sidx[qq][1] = i1; sidx[qq][2] = i2;
        sw[qq][0] = r0 * inv; sw[qq][1] = r1 * inv; sw[qq][2] = r2 * inv;
    }
    __syncthreads();

    // gather + interp + p1 cast. Wave wv handles rows wv, wv+4, ...
    const int wv = threadIdx.x >> 6, ln = threadIdx.x & 63;
    const size_t rowbase = (size_t)b * N_ + ntile * 64;
    const float* p2 = points2 + (size_t)b * S_ * C2_;
    for (int r = wv; r < 64; r += 4) {
        size_t orow = rowbase + r;
        int ia = sidx[r][0], ib = sidx[r][1], ic = sidx[r][2];
        float wa = sw[r][0], wb = sw[r][1], wc = sw[r][2];
        float4 va = *(const float4*)(p2 + (size_t)ia * C2_ + ln * 4);
        float4 vb = *(const float4*)(p2 + (size_t)ib * C2_ + ln * 4);
        float4 vc = *(const float4*)(p2 + (size_t)ic * C2_ + ln * 4);
        bf16x4 o = { (bf16)(wa * va.x + wb * vb.x + wc * vc.x),
                     (bf16)(wa * va.y + wb * vb.y + wc * vc.y),
                     (bf16)(wa * va.z + wb * vb.z + wc * vc.z),
                     (bf16)(wa * va.w + wb * vb.w + wc * vc.w) };
        *(bf16x4*)(Abf + orow * KA_ + C1_ + ln * 4) = o;

        float2 p = *(const float2*)(points1 + orow * C1_ + ln * 2);
        bf16x2 po = { (bf16)p.x, (bf16)p.y };
        *(bf16x2*)(Abf + orow * KA_ + ln * 2) = po;
    }
}

// ---------------- MFMA bf16 GEMM1 with fused BN-stats epilogue ------------------
template<int K, int OT, bool OUTBF>
__global__ __launch_bounds__(256) void mfma_gemm_kernel(
    const bf16* __restrict__ A, const bf16* __restrict__ Wt, void* __restrict__ Cout,
    float* __restrict__ sums, float* __restrict__ sumsq)
{
    __shared__ bf16 As[128 * 32];
    __shared__ bf16 Bs[128 * 32];
    __shared__ float csum[128], csumsq[128];
    const int tid = threadIdx.x;
    const int lane = tid & 63, wave = tid >> 6;
    const int wr = wave >> 1, wc = wave & 1;
    const int r0 = blockIdx.x * 128, o0 = blockIdx.y * 128;

    f32x4 acc[4][4] = {};

    const int l15 = lane & 15, g = lane >> 4;
    const int slot = g ^ ((l15 >> 1) & 3);
    int a_off[4], b_off[4];
    #pragma unroll
    for (int m = 0; m < 4; ++m) a_off[m] = (wr * 64 + m * 16 + l15) * 32 + slot * 8;
    #pragma unroll
    for (int n = 0; n < 4; ++n) b_off[n] = (wc * 64 + n * 16 + l15) * 32 + slot * 8;

    const int c0 = tid, c1 = tid + 256;
    const int ar0 = c0 >> 2, ar1 = c1 >> 2;
    const int kb0 = ((c0 & 3) ^ ((ar0 >> 1) & 3)) * 8;
    const int kb1 = ((c1 & 3) ^ ((ar1 >> 1) & 3)) * 8;

    if (tid < 128) { csum[tid] = 0.f; csumsq[tid] = 0.f; }

    for (int k0 = 0; k0 < K; k0 += 32) {
        __syncthreads();
        gload_lds16(A  + (size_t)(r0 + ar0) * K + k0 + kb0, &As[c0 * 8]);
        gload_lds16(A  + (size_t)(r0 + ar1) * K + k0 + kb1, &As[c1 * 8]);
        gload_lds16(Wt + (size_t)(o0 + ar0) * K + k0 + kb0, &Bs[c0 * 8]);
        gload_lds16(Wt + (size_t)(o0 + ar1) * K + k0 + kb1, &Bs[c1 * 8]);
        __syncthreads();
        bf16x8 af[4], bfr[4];
        #pragma unroll
        for (int m = 0; m < 4; ++m) af[m]  = *(const bf16x8*)&As[a_off[m]];
        #pragma unroll
        for (int n = 0; n < 4; ++n) bfr[n] = *(const bf16x8*)&Bs[b_off[n]];
        #pragma unroll
        for (int m = 0; m < 4; ++m)
            #pragma unroll
            for (int n = 0; n < 4; ++n)
                acc[m][n] = __builtin_amdgcn_mfma_f32_16x16x32_bf16(af[m], bfr[n], acc[m][n], 0, 0, 0);
    }

    const int crow = r0 + wr * 64 + g * 4;
    const int ccol = o0 + wc * 64 + l15;
    #pragma unroll
    for (int m = 0; m < 4; ++m)
        #pragma unroll
        for (int n = 0; n < 4; ++n)
            #pragma unroll
            for (int j = 0; j < 4; ++j) {
                size_t off = (size_t)(crow + m * 16 + j) * OT + ccol + n * 16;
                if (OUTBF) ((bf16*)Cout)[off] = (bf16)acc[m][n][j];
                else       ((float*)Cout)[off] = acc[m][n][j];
            }

    #pragma unroll
    for (int n = 0; n < 4; ++n) {
        float s = 0.f, q = 0.f;
        #pragma unroll
        for (int m = 0; m < 4; ++m)
            #pragma unroll
            for (int j = 0; j < 4; ++j) {
                float v = acc[m][n][j];
                s += v; q = fmaf(v, v, q);
            }
        int col = wc * 64 + n * 16 + l15;
        atomicAdd(&csum[col], s);
        atomicAdd(&csumsq[col], q);
    }
    __syncthreads();
    if (tid < 128) {
        atomicAdd(&sums[o0 + tid], csum[tid]);
        atomicAdd(&sumsq[o0 + tid], csumsq[tid]);
    }
}

// ---------------- MFMA GEMM2: inline finalize0 + BN+ReLU fused at A-staging -----
__global__ __launch_bounds__(256) void mfma_gemm2_kernel(
    const bf16* __restrict__ Ahp, const bf16* __restrict__ Wt,
    const float* __restrict__ sums0, const float* __restrict__ sumsq0,
    const float* __restrict__ g0, const float* __restrict__ be0,
    float* __restrict__ Cout, float* __restrict__ sums, float* __restrict__ sumsq)
{
    constexpr int K = H0_, OT = H1_;
    __shared__ bf16 As[128 * 32];
    __shared__ bf16 Bs[128 * 32];
    __shared__ float csum[128], csumsq[128];
    __shared__ float sscale[256], sshift[256];
    const int tid = threadIdx.x;
    const int lane = tid & 63, wave = tid >> 6;
    const int wr = wave >> 1, wc = wave & 1;
    const int r0 = blockIdx.x * 128, o0 = blockIdx.y * 128;

    {
        const float invR = 1.f / (float)R_;
        float mean = sums0[tid] * invR;
        float var = sumsq0[tid] * invR - mean * mean;
        float sv = g0[tid] * rsqrtf(var + 1e-5f);
        sscale[tid] = sv;
        sshift[tid] = be0[tid] - mean * sv;
    }
    if (tid < 128) { csum[tid] = 0.f; csumsq[tid] = 0.f; }
    __syncthreads();

    f32x4 acc[4][4] = {};

    const int l15 = lane & 15, g = lane >> 4;
    const int slot = g ^ ((l15 >> 1) & 3);
    int a_off[4], b_off[4];
    #pragma unroll
    for (int m = 0; m < 4; ++m) a_off[m] = (wr * 64 + m * 16 + l15) * 32 + slot * 8;
    #pragma unroll
    for (int n = 0; n < 4; ++n) b_off[n] = (wc * 64 + n * 16 + l15) * 32 + slot * 8;

    const int c0 = tid, c1 = tid + 256;
    const int ar0 = c0 >> 2, ar1 = c1 >> 2;
    const int kb0 = ((c0 & 3) ^ ((ar0 >> 1) & 3)) * 8;
    const int kb1 = ((c1 & 3) ^ ((ar1 >> 1) & 3)) * 8;

    for (int k0 = 0; k0 < K; k0 += 32) {
        bf16x8 va0 = *(const bf16x8*)(Ahp + (size_t)(r0 + ar0) * K + k0 + kb0);
        bf16x8 va1 = *(const bf16x8*)(Ahp + (size_t)(r0 + ar1) * K + k0 + kb1);
        float s0a[8], h0a[8], s1a[8], h1a[8];
        *(float4*)&s0a[0] = *(const float4*)(&sscale[k0 + kb0]);
        *(float4*)&s0a[4] = *(const float4*)(&sscale[k0 + kb0 + 4]);
        *(float4*)&h0a[0] = *(const float4*)(&sshift[k0 + kb0]);
        *(float4*)&h0a[4] = *(const float4*)(&sshift[k0 + kb0 + 4]);
        *(float4*)&s1a[0] = *(const float4*)(&sscale[k0 + kb1]);
        *(float4*)&s1a[4] = *(const float4*)(&sscale[k0 + kb1 + 4]);
        *(float4*)&h1a[0] = *(const float4*)(&sshift[k0 + kb1]);
        *(float4*)&h1a[4] = *(const float4*)(&sshift[k0 + kb1 + 4]);
        bf16x8 ra0, ra1;
        #pragma unroll
        for (int j = 0; j < 8; ++j) {
            float f0 = fmaxf(0.f, fmaf((float)va0[j], s0a[j], h0a[j]));
            float f1 = fmaxf(0.f, fmaf((float)va1[j], s1a[j], h1a[j]));
            ra0[j] = (bf16)f0; ra1[j] = (bf16)f1;
        }
        __syncthreads();
        gload_lds16(Wt + (size_t)(o0 + ar0) * K + k0 + kb0, &Bs[c0 * 8]);
        gload_lds16(Wt + (size_t)(o0 + ar1) * K + k0 + kb1, &Bs[c1 * 8]);
        *(bf16x8*)&As[c0 * 8] = ra0;
        *(bf16x8*)&As[c1 * 8] = ra1;
        __syncthreads();
        bf16x8 af[4], bfr[4];
        #pragma unroll
        for (int m = 0; m < 4; ++m) af[m]  = *(const bf16x8*)&As[a_off[m]];
        #pragma unroll
        for (int n = 0; n < 4; ++n) bfr[n] = *(const bf16x8*)&Bs[b_off[n]];
        #pragma unroll
        for (int m = 0; m < 4; ++m)
            #pragma unroll
            for (int n = 0; n < 4; ++n)
                acc[m][n] = __builtin_amdgcn_mfma_f32_16x16x32_bf16(af[m], bfr[n], acc[m][n], 0, 0, 0);
    }

    const int crow = r0 + wr * 64 + g * 4;
    const int ccol = o0 + wc * 64 + l15;
    #pragma unroll
    for (int m = 0; m < 4; ++m)
        #pragma unroll
        for (int n = 0; n < 4; ++n)
            #pragma unroll
            for (int j = 0; j < 4; ++j)
                ((float*)Cout)[(size_t)(crow + m * 16 + j) * OT + ccol + n * 16] = acc[m][n][j];

    #pragma unroll
    for (int n = 0; n < 4; ++n) {
        float s = 0.f, q = 0.f;
        #pragma unroll
        for (int m = 0; m < 4; ++m)
            #pragma unroll
            for (int j = 0; j < 4; ++j) {
                float v = acc[m][n][j];
                s += v; q = fmaf(v, v, q);
            }
        int col = wc * 64 + n * 16 + l15;
        atomicAdd(&csum[col], s);
        atomicAdd(&csumsq[col], q);
    }
    __syncthreads();
    if (tid < 128) {
        atomicAdd(&sums[o0 + tid], csum[tid]);
        atomicAdd(&sumsq[o0 + tid], csumsq[tid]);
    }
}

// ---------------- final BN+ReLU on d_out (f32), inline finalize1 ----------------
__global__ __launch_bounds__(256) void bnrelu_kernel(
    float* __restrict__ X, const float* __restrict__ sums1,
    const float* __restrict__ sumsq1, const float* __restrict__ g1,
    const float* __restrict__ be1)
{
    __shared__ float ss[128], sh[128];
    int tid = threadIdx.x;
    if (tid < 128) {
        const float invR = 1.f / (float)R_;
        float mean = sums1[tid] * invR;
        float var = sumsq1[tid] * invR - mean * mean;
        float sv = g1[tid] * rsqrtf(var + 1e-5f);
        ss[tid] = sv;
        sh[tid] = be1[tid] - mean * sv;
    }
    __syncthreads();

    #pragma unroll
    for (int it = 0; it < 4; ++it) {
        size_t i = (size_t)it * 524288 + (size_t)blockIdx.x * 256 + tid;  // float4 idx
        int c = ((int)i & 31) * 4;
        float4 v = *(float4*)(X + i * 4);
        v.x = fmaxf(0.f, v.x * ss[c + 0] + sh[c + 0]);
        v.y = fmaxf(0.f, v.y * ss[c + 1] + sh[c + 1]);
        v.z = fmaxf(0.f, v.z * ss[c + 2] + sh[c + 2]);
        v.w = fmaxf(0.f, v.w * ss[c + 3] + sh[c + 3]);
        *(float4*)(X + i * 4) = v;
    }
}

extern "C" void kernel_launch(void* const* d_in, const int* in_sizes, int n_in,
                              void* d_out, int out_size, void* d_ws, size_t ws_size,
                              hipStream_t stream)
{
    const float* xyz1    = (const float*)d_in[0];
    const float* xyz2    = (const float*)d_in[1];
    const float* points1 = (const float*)d_in[2];
    const float* points2 = (const float*)d_in[3];
    const float* w0  = (const float*)d_in[4];
    const float* g0  = (const float*)d_in[6];
    const float* be0 = (const float*)d_in[7];
    const float* w1  = (const float*)d_in[8];
    const float* g1  = (const float*)d_in[10];
    const float* be1 = (const float*)d_in[11];
    float* out = (float*)d_out;
    char* ws = (char*)d_ws;

    bf16* Abf     = (bf16*)(ws);                    // 65536*384*2
    bf16* hpre_bf = (bf16*)(ws + 50331648);         // 65536*256*2
    bf16* Wbf0    = (bf16*)(ws + 117440512);        // 256*384*2
    bf16* Wbf1    = (bf16*)(ws + 117637120);        // 128*256*2
    float* stats  = (float*)(ws + 119275520);       // 768*4
    float4* c4g   = (float4*)(ws + 119279616);      // 16384*16
    float* sums0 = stats,        *sumsq0 = stats + 256;
    float* sums1 = stats + 512,  *sumsq1 = stats + 640;

    prep_kernel<<<193, 256, 0, stream>>>(w0, w1, xyz2, Wbf0, Wbf1, stats, c4g);
    top3_interp_kernel<<<B_ * (N_ / 64), 256, 0, stream>>>(xyz1, c4g, points1, points2, Abf);

    mfma_gemm_kernel<KA_, H0_, true><<<dim3(R_ / 128, 2), 256, 0, stream>>>(
        Abf, Wbf0, hpre_bf, sums0, sumsq0);

    mfma_gemm2_kernel<<<dim3(R_ / 128, 1), 256, 0, stream>>>(
        hpre_bf, Wbf1, sums0, sumsq0, g0, be0, out, sums1, sumsq1);

    bnrelu_kernel<<<2048, 256, 0, stream>>>(out, sums1, sumsq1, g1, be1);
}